// Round 5
// baseline (4281.605 us; speedup 1.0000x reference)
//
#include <hip/hip_runtime.h>

typedef unsigned short u16;
typedef unsigned int   u32;

typedef __bf16 bf16x8 __attribute__((ext_vector_type(8)));
typedef float  f32x4  __attribute__((ext_vector_type(4)));
typedef u32    u32x4  __attribute__((ext_vector_type(4)));

#define B_ 32
#define S_ 512
#define I_ 512
#define H_ 1024
#define NB 64              // recurrent blocks; each owns 16 units
#define UB 16
#define CB 64              // gate-cols per block

#define XBF_U16  (S_ * B_ * I_)            // 8,388,608 u16 = 16.8 MB
#define HSLOT_B  65536                     // one h slot: [32 batch][1024 unit] bf16
#define RING_N   (S_ + 1)                  // slots 0..512 (0 unused: h0 = 0)
// bf16 NaN pair: h = sigmoid*tanh is ALWAYS finite -> payload can never be
// this pattern. Per-dword check is tear-proof (dword store atomicity).
#define POISON   0x7FC07FC0u

__device__ __forceinline__ u16 bf16bits(float f) {
    __bf16 b = (__bf16)f;                  // HW RNE convert
    return __builtin_bit_cast(u16, b);
}
__device__ __forceinline__ float sigmoid_(float x) { return 1.0f / (1.0f + __expf(-x)); }
__device__ __forceinline__ float tanh_(float x)    { return 2.0f / (1.0f + __expf(-2.0f * x)) - 1.0f; }
__device__ __forceinline__ u32 anyp(u32x4 v) {
    return (u32)(v[0] == POISON) | (u32)(v[1] == POISON) |
           (u32)(v[2] == POISON) | (u32)(v[3] == POISON);
}

// ============================================================================
// Kernel A: X [32][512][512] fp32 -> Xbf [t][batch][512] bf16 (t-major).
// ============================================================================
__global__ void __launch_bounds__(256)
xcvt(const float* __restrict__ X, u16* __restrict__ xbf)
{
    const int t = blockIdx.x, tid = threadIdx.x;
    #pragma unroll 4
    for (int b = 0; b < B_; ++b) {
        float2 v = *(const float2*)(X + (size_t)b * (S_ * I_) + (size_t)t * I_ + tid * 2);
        u32 pk = (u32)bf16bits(v.x) | ((u32)bf16bits(v.y) << 16);
        *(u32*)(xbf + (size_t)t * (B_ * I_) + b * I_ + tid * 2) = pk;
    }
}

// ============================================================================
// Kernel B (RING): barrier-free self-synchronizing recurrence.
// vs R4 (flag rendezvous, 5.6us/step): the per-step protocol chain
// {h-store drain -> flag propagate -> poll RT -> stage RT} (~4 serial IC
// round-trips x 64-party max-skew) collapses to ONE: the h data itself is
// the sync token. Ring slots 1..512 are pre-poisoned with bf16-NaN; readers
// stage with sc0sc1 loads and BATCH-retry only stale 128B granules (R2's
// convoy came from per-fragment SERIAL retries inside the MFMA loop — here
// retries are parallel, per-thread, and separated from compute). Producers:
// fire-and-forget dword stores. No flags, no drains, no per-step barriers
// beyond the 2 intra-block __syncthreads the LDS pipeline needs.
// Startup: each block poisons its own output region of slots 1..512, drains
// once, raises a ready flag; all blocks rendezvous ONCE on the 64 flags
// (ws harness-poison 0xAA can't be trusted as our sentinel).
// ============================================================================
__global__ void __launch_bounds__(512, 2)
lstm_ring(const u16* __restrict__ xbf,
          const float* __restrict__ u_i, const float* __restrict__ b_i,
          const float* __restrict__ u_f, const float* __restrict__ b_f,
          const float* __restrict__ u_c, const float* __restrict__ b_c,
          const float* __restrict__ u_o, const float* __restrict__ b_o,
          const float* __restrict__ w_i, const float* __restrict__ w_f,
          const float* __restrict__ w_c, const float* __restrict__ w_o,
          float* __restrict__ out, u16* __restrict__ ring, u32* __restrict__ rdy)
{
    __shared__ __align__(16) char  hx[32 * 3072];      // [batch][2048B h | 1024B x]
    __shared__ __align__(16) float gb[4][32][68];      // per-K-quarter gate partials

    const int tid  = threadIdx.x;
    const int bid  = blockIdx.x;
    const int wave = tid >> 6;
    const int lane = tid & 63;
    const int quad = lane >> 4;
    const int l16  = lane & 15;
    const int cg   = wave & 1;        // col group
    const int kq   = wave >> 1;       // K quarter

    // ---- poison own output region of slots 1..512 (64 granules/slot-region,
    // 64 iters x 512 threads covers 512 regions) ----
    {
        u32x4 pz; pz[0] = pz[1] = pz[2] = pz[3] = POISON;
        #pragma unroll 4
        for (int i = 0; i < 64; ++i) {
            const int gidx = tid + i * 512;        // 0..32767
            const int s    = 1 + (gidx >> 6);      // slot 1..512
            const int idx  = gidx & 63;
            const int row  = idx >> 1, half = idx & 1;
            char* pp = (char*)ring + (size_t)s * HSLOT_B + row * 2048 + bid * 32 + half * 16;
            asm volatile("global_store_dwordx4 %0, %1, off sc0 sc1"
                         :: "v"(pp), "v"(pz) : "memory");
        }
    }

    // ---- B fragments (U then W), 2 colsets x 12 kb = 96 VGPRs ----
    bf16x8 bfr[2][12];
    #pragma unroll
    for (int cs = 0; cs < 2; ++cs) {
        const int gc = bid * CB + cg * 32 + cs * 16 + l16;
        const int ug = gc >> 2, g = gc & 3;
        const float* Up = ((g == 0) ? u_i : (g == 1) ? u_f : (g == 2) ? u_c : u_o) + ug;
        const float* Wp = ((g == 0) ? w_i : (g == 1) ? w_f : (g == 2) ? w_c : w_o) + ug;
        #pragma unroll
        for (int kb = 0; kb < 12; ++kb) {
            const int kbg = kq * 12 + kb;
            #pragma unroll
            for (int j = 0; j < 8; ++j) {
                const int k = kbg * 32 + quad * 8 + j;
                bfr[cs][kb][j] = (k < 1024) ? (__bf16)Up[(size_t)k * H_]
                                            : (__bf16)Wp[(size_t)(k - 1024) * H_];
            }
        }
    }

    // ---- one-time rendezvous: poison visible before anyone can read it ----
    asm volatile("s_waitcnt vmcnt(0)" ::: "memory");
    if (tid == 0) {
        u32* rp = rdy + bid * 16; u32 one = 1u;
        asm volatile("global_store_dword %0, %1, off sc0 sc1" :: "v"(rp), "v"(one) : "memory");
    }
    if (wave == 0) {
        const u32* rp = rdy + lane * 16;
        u32 v;
        do {
            asm volatile("global_load_dword %0, %1, off sc0 sc1\n\ts_waitcnt vmcnt(0)"
                         : "=v"(v) : "v"(rp) : "memory");
        } while ((int)v < 1);                      // 0xAAAAAAAA poison < 1
    }
    asm volatile("s_barrier" ::: "memory");

    // ---- maps ----
    const int srow = tid & 31;                     // staging row (batch)
    const int sch  = tid >> 5;                     // 0..15: 128B h chunk / 64B x chunk
    const int skey = (srow & 7) << 4;
    char* sdst = hx + srow * 3072;
    const int akey = (l16 & 7) << 4;

    const int ub2  = tid >> 4;                     // update: batch
    const int uq   = tid & 15;                     // update: unit-in-block
    const int unit = bid * UB + uq;
    const float bia = b_i[unit], bif = b_f[unit], bic = b_c[unit], bio = b_o[unit];
    float cst = 0.0f;

    for (int t = 0; t < S_; ++t) {
        // x prefetch (plain, cached)
        const u32x4* xsrc = (const u32x4*)(xbf + (size_t)t * (B_ * I_) + srow * I_ + sch * 32);
        u32x4 xv0 = xsrc[0], xv1 = xsrc[1], xv2 = xsrc[2], xv3 = xsrc[3];

        if (t) {
            // ---- stage h(t): batch poison-retry, one parallel RT per round
            const char* hsrc = (const char*)ring + (size_t)t * HSLOT_B + srow * 2048 + sch * 128;
            u32x4 h0, h1, h2, h3, h4, h5, h6, h7;
            for (;;) {
                asm volatile(
                    "global_load_dwordx4 %0, %8, off sc0 sc1\n\t"
                    "global_load_dwordx4 %1, %8, off offset:16 sc0 sc1\n\t"
                    "global_load_dwordx4 %2, %8, off offset:32 sc0 sc1\n\t"
                    "global_load_dwordx4 %3, %8, off offset:48 sc0 sc1\n\t"
                    "global_load_dwordx4 %4, %8, off offset:64 sc0 sc1\n\t"
                    "global_load_dwordx4 %5, %8, off offset:80 sc0 sc1\n\t"
                    "global_load_dwordx4 %6, %8, off offset:96 sc0 sc1\n\t"
                    "global_load_dwordx4 %7, %8, off offset:112 sc0 sc1\n\t"
                    "s_waitcnt vmcnt(0)"
                    : "=&v"(h0), "=&v"(h1), "=&v"(h2), "=&v"(h3),
                      "=&v"(h4), "=&v"(h5), "=&v"(h6), "=&v"(h7)
                    : "v"(hsrc) : "memory");
                if (!(anyp(h0) | anyp(h1) | anyp(h2) | anyp(h3) |
                      anyp(h4) | anyp(h5) | anyp(h6) | anyp(h7))) break;
            }
            *(u32x4*)(sdst + ((sch * 128 +   0) ^ skey)) = h0;
            *(u32x4*)(sdst + ((sch * 128 +  16) ^ skey)) = h1;
            *(u32x4*)(sdst + ((sch * 128 +  32) ^ skey)) = h2;
            *(u32x4*)(sdst + ((sch * 128 +  48) ^ skey)) = h3;
            *(u32x4*)(sdst + ((sch * 128 +  64) ^ skey)) = h4;
            *(u32x4*)(sdst + ((sch * 128 +  80) ^ skey)) = h5;
            *(u32x4*)(sdst + ((sch * 128 +  96) ^ skey)) = h6;
            *(u32x4*)(sdst + ((sch * 128 + 112) ^ skey)) = h7;
        } else {
            u32x4 z = {0u, 0u, 0u, 0u};
            #pragma unroll
            for (int i = 0; i < 8; ++i)
                *(u32x4*)(sdst + ((sch * 128 + i * 16) ^ skey)) = z;
        }
        // stage x
        *(u32x4*)(sdst + ((2048 + sch * 64 +  0) ^ skey)) = xv0;
        *(u32x4*)(sdst + ((2048 + sch * 64 + 16) ^ skey)) = xv1;
        *(u32x4*)(sdst + ((2048 + sch * 64 + 32) ^ skey)) = xv2;
        *(u32x4*)(sdst + ((2048 + sch * 64 + 48) ^ skey)) = xv3;
        __syncthreads();

        // ---- MFMA: 12 kb x 2 row-tiles x 2 colsets = 48 per wave
        f32x4 a00 = {0.f, 0.f, 0.f, 0.f}, a01 = {0.f, 0.f, 0.f, 0.f};
        f32x4 a10 = {0.f, 0.f, 0.f, 0.f}, a11 = {0.f, 0.f, 0.f, 0.f};
        #pragma unroll
        for (int kb = 0; kb < 12; ++kb) {
            const int off = (kq * 12 + kb) * 64 + quad * 16;
            bf16x8 A0 = *(const bf16x8*)(hx + l16 * 3072 + (off ^ akey));
            bf16x8 A1 = *(const bf16x8*)(hx + (16 + l16) * 3072 + (off ^ akey));
            a00 = __builtin_amdgcn_mfma_f32_16x16x32_bf16(A0, bfr[0][kb], a00, 0, 0, 0);
            a10 = __builtin_amdgcn_mfma_f32_16x16x32_bf16(A1, bfr[0][kb], a10, 0, 0, 0);
            a01 = __builtin_amdgcn_mfma_f32_16x16x32_bf16(A0, bfr[1][kb], a01, 0, 0, 0);
            a11 = __builtin_amdgcn_mfma_f32_16x16x32_bf16(A1, bfr[1][kb], a11, 0, 0, 0);
        }
        #pragma unroll
        for (int r = 0; r < 4; ++r) {
            gb[kq][quad * 4 + r][cg * 32 + l16]           = a00[r];
            gb[kq][quad * 4 + r][cg * 32 + 16 + l16]      = a01[r];
            gb[kq][16 + quad * 4 + r][cg * 32 + l16]      = a10[r];
            gb[kq][16 + quad * 4 + r][cg * 32 + 16 + l16] = a11[r];
        }
        __syncthreads();

        // ---- update: 1 (batch, unit) per thread
        f32x4 s0 = *(const f32x4*)&gb[0][ub2][uq * 4];
        f32x4 s1 = *(const f32x4*)&gb[1][ub2][uq * 4];
        f32x4 s2 = *(const f32x4*)&gb[2][ub2][uq * 4];
        f32x4 s3 = *(const f32x4*)&gb[3][ub2][uq * 4];
        f32x4 sg = s0 + s1 + s2 + s3;
        const float gi = sg[0] + bia, gf = sg[1] + bif;
        const float gc2 = sg[2] + bic, go = sg[3] + bio;
        cst = sigmoid_(gf) * cst + sigmoid_(gi) * tanh_(gc2);
        const float h = sigmoid_(go) * tanh_(cst);
        const float hn = __shfl_xor(h, 1);

        // ---- publish h(t+1): fire-and-forget; the data IS the token
        if ((tid & 1) == 0) {
            u32 pk = (u32)bf16bits(h) | ((u32)bf16bits(hn) << 16);
            char* hp = (char*)ring + (size_t)(t + 1) * HSLOT_B + ub2 * 2048 + unit * 2;
            asm volatile("global_store_dword %0, %1, off sc0 sc1"
                         :: "v"(hp), "v"(pk) : "memory");
            float2 o2; o2.x = h; o2.y = hn;
            *(float2*)(out + (size_t)ub2 * (S_ * H_) + (size_t)t * H_ + unit) = o2;
        }
        if (t == S_ - 1) {
            const float cn = __shfl_xor(cst, 1);
            if ((tid & 1) == 0) {
                float2 hf; hf.x = h;   hf.y = hn;
                float2 cf; cf.x = cst; cf.y = cn;
                *(float2*)(out + (size_t)B_ * S_ * H_ + ub2 * H_ + unit) = hf;
                *(float2*)(out + (size_t)B_ * S_ * H_ + B_ * H_ + ub2 * H_ + unit) = cf;
            }
        }
    }
}

// ============================================================================
// FALLBACK (small ws): R4 flag-rendezvous kernel, verbatim (proven 2992us).
// ============================================================================
__global__ void __launch_bounds__(512, 2)
lstm_rec(const u16* __restrict__ xbf,
         const float* __restrict__ u_i, const float* __restrict__ b_i,
         const float* __restrict__ u_f, const float* __restrict__ b_f,
         const float* __restrict__ u_c, const float* __restrict__ b_c,
         const float* __restrict__ u_o, const float* __restrict__ b_o,
         const float* __restrict__ w_i, const float* __restrict__ w_f,
         const float* __restrict__ w_c, const float* __restrict__ w_o,
         float* __restrict__ out, u16* __restrict__ hsl, u32* __restrict__ flags)
{
    __shared__ __align__(16) char  hx[32 * 3072];
    __shared__ __align__(16) float gb[4][32][68];

    const int tid  = threadIdx.x;
    const int bid  = blockIdx.x;
    const int wave = tid >> 6;
    const int lane = tid & 63;
    const int quad = lane >> 4;
    const int l16  = lane & 15;
    const int cg   = wave & 1;
    const int kq   = wave >> 1;

    bf16x8 bfr[2][12];
    #pragma unroll
    for (int cs = 0; cs < 2; ++cs) {
        const int gc = bid * CB + cg * 32 + cs * 16 + l16;
        const int ug = gc >> 2, g = gc & 3;
        const float* Up = ((g == 0) ? u_i : (g == 1) ? u_f : (g == 2) ? u_c : u_o) + ug;
        const float* Wp = ((g == 0) ? w_i : (g == 1) ? w_f : (g == 2) ? w_c : w_o) + ug;
        #pragma unroll
        for (int kb = 0; kb < 12; ++kb) {
            const int kbg = kq * 12 + kb;
            #pragma unroll
            for (int j = 0; j < 8; ++j) {
                const int k = kbg * 32 + quad * 8 + j;
                bfr[cs][kb][j] = (k < 1024) ? (__bf16)Up[(size_t)k * H_]
                                            : (__bf16)Wp[(size_t)(k - 1024) * H_];
            }
        }
    }

    const int srow = tid & 31;
    const int sch  = tid >> 5;
    const int skey = (srow & 7) << 4;
    char* sdst = hx + srow * 3072;
    const int akey = (l16 & 7) << 4;

    const int ub2  = tid >> 4;
    const int uq   = tid & 15;
    const int unit = bid * UB + uq;
    const float bia = b_i[unit], bif = b_f[unit], bic = b_c[unit], bio = b_o[unit];
    float cst = 0.0f;

    for (int t = 0; t < S_; ++t) {
        const u32x4* xsrc = (const u32x4*)(xbf + (size_t)t * (B_ * I_) + srow * I_ + sch * 32);
        u32x4 xv0 = xsrc[0], xv1 = xsrc[1], xv2 = xsrc[2], xv3 = xsrc[3];

        if (t) {
            if (wave == 0) {
                const u32* fp = flags + lane * 16;
                u32 v;
                do {
                    asm volatile("global_load_dword %0, %1, off sc0 sc1\n\t"
                                 "s_waitcnt vmcnt(0)"
                                 : "=v"(v) : "v"(fp) : "memory");
                } while ((int)v < t);
            }
            asm volatile("s_barrier" ::: "memory");

            const char* hsrc = (const char*)hsl + (size_t)(t & 1) * HSLOT_B
                               + srow * 2048 + sch * 128;
            u32x4 h0, h1, h2, h3, h4, h5, h6, h7;
            asm volatile(
                "global_load_dwordx4 %0, %8, off sc0 sc1\n\t"
                "global_load_dwordx4 %1, %8, off offset:16 sc0 sc1\n\t"
                "global_load_dwordx4 %2, %8, off offset:32 sc0 sc1\n\t"
                "global_load_dwordx4 %3, %8, off offset:48 sc0 sc1\n\t"
                "global_load_dwordx4 %4, %8, off offset:64 sc0 sc1\n\t"
                "global_load_dwordx4 %5, %8, off offset:80 sc0 sc1\n\t"
                "global_load_dwordx4 %6, %8, off offset:96 sc0 sc1\n\t"
                "global_load_dwordx4 %7, %8, off offset:112 sc0 sc1\n\t"
                "s_waitcnt vmcnt(0)"
                : "=&v"(h0), "=&v"(h1), "=&v"(h2), "=&v"(h3),
                  "=&v"(h4), "=&v"(h5), "=&v"(h6), "=&v"(h7)
                : "v"(hsrc) : "memory");
            *(u32x4*)(sdst + ((sch * 128 +   0) ^ skey)) = h0;
            *(u32x4*)(sdst + ((sch * 128 +  16) ^ skey)) = h1;
            *(u32x4*)(sdst + ((sch * 128 +  32) ^ skey)) = h2;
            *(u32x4*)(sdst + ((sch * 128 +  48) ^ skey)) = h3;
            *(u32x4*)(sdst + ((sch * 128 +  64) ^ skey)) = h4;
            *(u32x4*)(sdst + ((sch * 128 +  80) ^ skey)) = h5;
            *(u32x4*)(sdst + ((sch * 128 +  96) ^ skey)) = h6;
            *(u32x4*)(sdst + ((sch * 128 + 112) ^ skey)) = h7;
        } else {
            u32x4 z = {0u, 0u, 0u, 0u};
            #pragma unroll
            for (int i = 0; i < 8; ++i)
                *(u32x4*)(sdst + ((sch * 128 + i * 16) ^ skey)) = z;
        }
        *(u32x4*)(sdst + ((2048 + sch * 64 +  0) ^ skey)) = xv0;
        *(u32x4*)(sdst + ((2048 + sch * 64 + 16) ^ skey)) = xv1;
        *(u32x4*)(sdst + ((2048 + sch * 64 + 32) ^ skey)) = xv2;
        *(u32x4*)(sdst + ((2048 + sch * 64 + 48) ^ skey)) = xv3;
        __syncthreads();

        f32x4 a00 = {0.f, 0.f, 0.f, 0.f}, a01 = {0.f, 0.f, 0.f, 0.f};
        f32x4 a10 = {0.f, 0.f, 0.f, 0.f}, a11 = {0.f, 0.f, 0.f, 0.f};
        #pragma unroll
        for (int kb = 0; kb < 12; ++kb) {
            const int off = (kq * 12 + kb) * 64 + quad * 16;
            bf16x8 A0 = *(const bf16x8*)(hx + l16 * 3072 + (off ^ akey));
            bf16x8 A1 = *(const bf16x8*)(hx + (16 + l16) * 3072 + (off ^ akey));
            a00 = __builtin_amdgcn_mfma_f32_16x16x32_bf16(A0, bfr[0][kb], a00, 0, 0, 0);
            a10 = __builtin_amdgcn_mfma_f32_16x16x32_bf16(A1, bfr[0][kb], a10, 0, 0, 0);
            a01 = __builtin_amdgcn_mfma_f32_16x16x32_bf16(A0, bfr[1][kb], a01, 0, 0, 0);
            a11 = __builtin_amdgcn_mfma_f32_16x16x32_bf16(A1, bfr[1][kb], a11, 0, 0, 0);
        }
        #pragma unroll
        for (int r = 0; r < 4; ++r) {
            gb[kq][quad * 4 + r][cg * 32 + l16]           = a00[r];
            gb[kq][quad * 4 + r][cg * 32 + 16 + l16]      = a01[r];
            gb[kq][16 + quad * 4 + r][cg * 32 + l16]      = a10[r];
            gb[kq][16 + quad * 4 + r][cg * 32 + 16 + l16] = a11[r];
        }
        __syncthreads();

        f32x4 s0 = *(const f32x4*)&gb[0][ub2][uq * 4];
        f32x4 s1 = *(const f32x4*)&gb[1][ub2][uq * 4];
        f32x4 s2 = *(const f32x4*)&gb[2][ub2][uq * 4];
        f32x4 s3 = *(const f32x4*)&gb[3][ub2][uq * 4];
        f32x4 sg = s0 + s1 + s2 + s3;
        const float gi = sg[0] + bia, gf = sg[1] + bif;
        const float gc2 = sg[2] + bic, go = sg[3] + bio;
        cst = sigmoid_(gf) * cst + sigmoid_(gi) * tanh_(gc2);
        const float h = sigmoid_(go) * tanh_(cst);
        const float hn = __shfl_xor(h, 1);

        if ((tid & 1) == 0) {
            u32 pk = (u32)bf16bits(h) | ((u32)bf16bits(hn) << 16);
            char* hp = (char*)hsl + (size_t)((t + 1) & 1) * HSLOT_B + ub2 * 2048 + unit * 2;
            asm volatile("global_store_dword %0, %1, off sc0 sc1"
                         :: "v"(hp), "v"(pk) : "memory");
        }
        asm volatile("s_waitcnt vmcnt(0)" ::: "memory");
        asm volatile("s_barrier" ::: "memory");
        if (tid == 0) {
            u32* fp = flags + bid * 16;
            u32 fv = (u32)(t + 1);
            asm volatile("global_store_dword %0, %1, off sc0 sc1"
                         :: "v"(fp), "v"(fv) : "memory");
        }

        if ((tid & 1) == 0) {
            float2 o2; o2.x = h; o2.y = hn;
            *(float2*)(out + (size_t)ub2 * (S_ * H_) + (size_t)t * H_ + unit) = o2;
        }
        if (t == S_ - 1) {
            const float cn = __shfl_xor(cst, 1);
            if ((tid & 1) == 0) {
                float2 hf; hf.x = h;   hf.y = hn;
                float2 cf; cf.x = cst; cf.y = cn;
                *(float2*)(out + (size_t)B_ * S_ * H_ + ub2 * H_ + unit) = hf;
                *(float2*)(out + (size_t)B_ * S_ * H_ + B_ * H_ + ub2 * H_ + unit) = cf;
            }
        }
    }
}

extern "C" void kernel_launch(void* const* d_in, const int* in_sizes, int n_in,
                              void* d_out, int out_size, void* d_ws, size_t ws_size,
                              hipStream_t stream) {
    const float* X   = (const float*)d_in[0];
    const float* w_i = (const float*)d_in[1];
    const float* u_i = (const float*)d_in[2];
    const float* b_i = (const float*)d_in[3];
    const float* w_f = (const float*)d_in[4];
    const float* u_f = (const float*)d_in[5];
    const float* b_f = (const float*)d_in[6];
    const float* w_c = (const float*)d_in[7];
    const float* u_c = (const float*)d_in[8];
    const float* b_c = (const float*)d_in[9];
    const float* w_o = (const float*)d_in[10];
    const float* u_o = (const float*)d_in[11];
    const float* b_o = (const float*)d_in[12];
    float* out = (float*)d_out;

    const size_t xbf_b  = (size_t)XBF_U16 * 2;                 // 16.8 MB
    const size_t ring_b = (size_t)RING_N * HSLOT_B;            // 33.6 MB
    u16* xbf = (u16*)d_ws;

    hipLaunchKernelGGL(xcvt, dim3(S_), dim3(256), 0, stream, X, xbf);

    if (ws_size >= xbf_b + ring_b + 8192) {
        // RING path: ws = Xbf | ring(513 x 64KB) | rdy(64 cells, 64B stride)
        u16* ring = (u16*)((char*)d_ws + xbf_b);
        u32* rdy  = (u32*)((char*)d_ws + xbf_b + ring_b);
        hipLaunchKernelGGL(lstm_ring, dim3(NB), dim3(512), 0, stream,
                           xbf, u_i, b_i, u_f, b_f, u_c, b_c, u_o, b_o,
                           w_i, w_f, w_c, w_o, out, ring, rdy);
    } else {
        // fallback: R4 flag-rendezvous (2-slot ping-pong)
        u16* hsl   = (u16*)((char*)d_ws + xbf_b);
        u32* flags = (u32*)((char*)d_ws + xbf_b + 2 * HSLOT_B);
        hipLaunchKernelGGL(lstm_rec, dim3(NB), dim3(512), 0, stream,
                           xbf, u_i, b_i, u_f, b_f, u_c, b_c, u_o, b_o,
                           w_i, w_f, w_c, w_o, out, hsl, flags);
    }
}